// Round 10
// baseline (589.066 us; speedup 1.0000x reference)
//
#include <hip/hip_runtime.h>
#include <hip/hip_bf16.h>

#define HH 128
#define NN 1024
#define KNBR 30
#define NV 21
#define LEPS 1e-5f

typedef unsigned short ushort_t;
typedef __attribute__((ext_vector_type(8))) short short8;
typedef __attribute__((ext_vector_type(4))) short shortv4;
typedef __attribute__((ext_vector_type(4))) float f32x4;

__device__ __forceinline__ ushort_t f2us(float f) {
  __hip_bfloat16 h = __float2bfloat16(f);
  return __builtin_bit_cast(unsigned short, h);
}
__device__ __forceinline__ float us2f(ushort_t u) {
  __hip_bfloat16 h = __builtin_bit_cast(__hip_bfloat16, u);
  return __bfloat162float(h);
}

// XOR-swizzled LDS helpers (row-major, rowB bytes/row, swizzle within 128B)
__device__ __forceinline__ void sw_store8(ushort_t* base, int row, int rowB, int colByte, short8 v) {
  int byte = row * rowB + colByte;
  byte ^= (row & 7) << 4;
  *(short8*)((char*)base + byte) = v;
}
__device__ __forceinline__ short8 sw_load8(const ushort_t* base, int row, int rowB, int colByte) {
  int byte = row * rowB + colByte;
  byte ^= (row & 7) << 4;
  return *(const short8*)((const char*)base + byte);
}
__device__ __forceinline__ void sw_store1(ushort_t* base, int row, int rowB, int col, ushort_t v) {
  int byte = row * rowB + col * 2;
  byte ^= (row & 7) << 4;
  *(ushort_t*)((char*)base + byte) = v;
}

// ---------------- merged weight prep: 32 tensors in one launch ----------------
// frag idx: ((k>>5)*NT + (c>>4))*512 + (((k&31)>>3)*16 + (c&15))*8 + (k&7)
struct PrepTab {
  const float* src[32];
  unsigned dstOff[32];
  int blk0[32];     // starting block of each tensor (each block = 256 elems)
  int nshift[32];
};

__global__ __launch_bounds__(256) void k_prep_all(PrepTab tab, ushort_t* __restrict__ dst) {
  const int bid = blockIdx.x;
  int ti = 0;
#pragma unroll 1
  for (int i = 1; i < 32; ++i)
    if (bid >= tab.blk0[i]) ti = i;
  const int nshift = tab.nshift[ti];
  const int e = (bid - tab.blk0[ti]) * 256 + threadIdx.x;
  const int k = e >> nshift;
  const int c = e & ((1 << nshift) - 1);
  const int NT = 1 << (nshift - 4);
  const int idx = ((k >> 5) * NT + (c >> 4)) * 512 + (((k & 31) >> 3) * 16 + (c & 15)) * 8 + (k & 7);
  dst[tab.dstOff[ti] + idx] = f2us(tab.src[ti][e]);
}

// ---------------- 128x128x128 MFMA GEMM over row tiles, bf16 out ----------------
__global__ __launch_bounds__(256) void k_gemm128(
    const float* __restrict__ A, const ushort_t* __restrict__ Wf,
    const float* __restrict__ bias, ushort_t* __restrict__ out)
{
  const int t = threadIdx.x, wid = t >> 6, lane = t & 63;
  const int wm = wid >> 1, wn = wid & 1;
  const size_t row0 = (size_t)blockIdx.x * 128;
  __shared__ alignas(16) ushort_t Xs[128 * 128];  // 32KB, rowB=256

  // stage A tile (f32 -> bf16, swizzled): thread covers 64 floats = 8 x short8
  {
    const int row = t >> 1, half = t & 1;
    const float4* p = (const float4*)(A + (row0 + row) * HH + half * 64);
#pragma unroll
    for (int i = 0; i < 8; ++i) {
      short8 wv;
#pragma unroll
      for (int jj = 0; jj < 2; ++jj) {
        const float4 x = p[i * 2 + jj];
        wv[jj * 4 + 0] = (short)f2us(x.x);
        wv[jj * 4 + 1] = (short)f2us(x.y);
        wv[jj * 4 + 2] = (short)f2us(x.z);
        wv[jj * 4 + 3] = (short)f2us(x.w);
      }
      sw_store8(Xs, row, 256, half * 128 + i * 16, wv);
    }
  }
  __syncthreads();

  f32x4 acc[4][4];
#pragma unroll
  for (int ni = 0; ni < 4; ++ni) {
    const float bv = bias[wn * 64 + ni * 16 + (lane & 15)];
#pragma unroll
    for (int mi = 0; mi < 4; ++mi) acc[mi][ni] = {bv, bv, bv, bv};
  }
#pragma unroll
  for (int kb = 0; kb < 4; ++kb) {
    short8 Af[4], Bf[4];
#pragma unroll
    for (int mi = 0; mi < 4; ++mi)
      Af[mi] = sw_load8(Xs, wm * 64 + mi * 16 + (lane & 15), 256, kb * 64 + (lane >> 4) * 16);
#pragma unroll
    for (int ni = 0; ni < 4; ++ni)
      Bf[ni] = *(const short8*)&Wf[(((size_t)kb * 8 + wn * 4 + ni) * 64 + lane) * 8];
#pragma unroll
    for (int mi = 0; mi < 4; ++mi)
#pragma unroll
      for (int ni = 0; ni < 4; ++ni)
        acc[mi][ni] = __builtin_amdgcn_mfma_f32_16x16x32_bf16(Af[mi], Bf[ni], acc[mi][ni], 0, 0, 0);
  }

  __syncthreads();  // done reading Xs
#pragma unroll
  for (int mi = 0; mi < 4; ++mi)
#pragma unroll
    for (int ni = 0; ni < 4; ++ni)
#pragma unroll
      for (int q = 0; q < 4; ++q) {
        const int row = wm * 64 + mi * 16 + (lane >> 4) * 4 + q;
        const int col = wn * 64 + ni * 16 + (lane & 15);
        sw_store1(Xs, row, 256, col, f2us(acc[mi][ni][q]));
      }
  __syncthreads();
  {
    const int row = t >> 1, half = t & 1;
    ushort_t* o = out + (row0 + row) * HH + half * 64;
#pragma unroll
    for (int i = 0; i < 8; ++i)
      *(short8*)(o + i * 8) = sw_load8(Xs, row, 256, half * 128 + i * 16);
  }
}

// ---------------- h_S = Ws_emb[S] (bf16), vectorized gather ----------------
__global__ __launch_bounds__(256) void k_hs(
    const int* __restrict__ S, const float* __restrict__ Wse, ushort_t* __restrict__ hS)
{
  const int e = blockIdx.x * 256 + threadIdx.x;  // 4-elem groups, total 8192*32
  const int r = e >> 5, cq = e & 31;
  const float4 x = *(const float4*)(Wse + (size_t)S[r] * HH + cq * 4);
  shortv4 v;
  v[0] = (short)f2us(x.x); v[1] = (short)f2us(x.y);
  v[2] = (short)f2us(x.z); v[3] = (short)f2us(x.w);
  *(shortv4*)(hS + (size_t)r * HH + cq * 4) = v;
}

// ---------------- MFMA message kernel: WAVE-INDEPENDENT, 1 node/wave ----------------
// Each wave owns node = blockIdx.x*4 + wid: a 32x128 output tile (32 edge rows).
// All LDS (X dbuf, Y, meta, dh) is wave-private -> ZERO __syncthreads.
// In-wave ds_write -> ds_read ordering is guaranteed by the in-order LDS pipe.
template <int DEC>
__global__ __launch_bounds__(256) void k_msg(
    const ushort_t* __restrict__ hV_in, const ushort_t* __restrict__ hV_enc,
    const ushort_t* __restrict__ hS, const ushort_t* __restrict__ hE,
    const ushort_t* __restrict__ W1f, const ushort_t* __restrict__ W2f,
    const ushort_t* __restrict__ W3f,
    const float* __restrict__ b1, const float* __restrict__ b2,
    const float* __restrict__ b3,
    const float* __restrict__ g1, const float* __restrict__ bt1,
    const int* __restrict__ E_idx, const float* __restrict__ mask,
    ushort_t* __restrict__ h1out)
{
  constexpr int INF = DEC ? 4 * HH : 3 * HH;
  constexpr int SLABS = INF / 64;
  const int t = threadIdx.x;
  const int wid = t >> 6, lane = t & 63;
  const int node = blockIdx.x * 4 + wid;
  const int bb = node >> 10;
  const int np = node & (NN - 1);

  __shared__ alignas(16) ushort_t Tile[4][4096];  // 8KB per wave: {Xa|Xb} then Y
  __shared__ int s_nb[4][32];
  __shared__ float s_watt[4][32];
  __shared__ signed char s_ar[4][32];
  __shared__ float s_dh[4][128];

  ushort_t* Xa = Tile[wid];              // [32][64] rowB=128 (4KB)
  ushort_t* Xb = Tile[wid] + 2048;       // 4KB
  ushort_t* Yw = Tile[wid];              // [32][128] rowB=256 (8KB, after GEMM1)

  // ---- wave-local meta (consumed only by this wave; in-order LDS) ----
  if (lane < 32) {
    int nb = 0, arI = 0;
    float watt = 0.f;
    if (lane < KNBR) {
      nb = E_idx[(size_t)node * KNBR + lane];
      if (DEC) {
        arI = (nb < np) ? 1 : 0;
        watt = 1.f;
      } else {
        watt = mask[node] * mask[bb * NN + nb];
      }
    }
    s_nb[wid][lane] = nb; s_watt[wid][lane] = watt; s_ar[wid][lane] = (signed char)arI;
  }

  // per-lane staging geometry: row sr (edge slot), half of 64 cols
  const int sr = lane >> 1, shalf = lane & 1;
  const bool srv = (sr < KNBR);
  const int snb = s_nb[wid][sr];
  const bool sar = (bool)s_ar[wid][sr];

  auto src_of = [&](int s) -> const ushort_t* {
    if (!srv) return nullptr;
    const int fc0 = s * 64 + shalf * 32;
    const int seg = fc0 >> 7, off = fc0 & 127;
    if (seg == 0) return hV_in + (size_t)node * HH + off;
    if (seg == 1) return hE + ((size_t)node * KNBR + sr) * HH + off;
    if (seg == 2) {
      if (DEC) return sar ? (hS + (size_t)(bb * NN + snb) * HH + off) : nullptr;
      return hV_in + (size_t)(bb * NN + snb) * HH + off;
    }
    return (sar ? hV_in : hV_enc) + (size_t)(bb * NN + snb) * HH + off;
  };

  f32x4 acc[2][8];
#pragma unroll
  for (int ni = 0; ni < 8; ++ni) {
    const float bv = b1[ni * 16 + (lane & 15)];
#pragma unroll
    for (int mi = 0; mi < 2; ++mi) acc[mi][ni] = {bv, bv, bv, bv};
  }

  // ---- GEMM1: wave-private double-buffered slabs, no barriers ----
  {
    const short8 z8 = {0, 0, 0, 0, 0, 0, 0, 0};
    {
      const ushort_t* src = src_of(0);
      short8 v0 = z8, v1 = z8, v2 = z8, v3 = z8;
      if (src) { const short8* p = (const short8*)src; v0 = p[0]; v1 = p[1]; v2 = p[2]; v3 = p[3]; }
      sw_store8(Xa, sr, 128, shalf * 64 + 0, v0);
      sw_store8(Xa, sr, 128, shalf * 64 + 16, v1);
      sw_store8(Xa, sr, 128, shalf * 64 + 32, v2);
      sw_store8(Xa, sr, 128, shalf * 64 + 48, v3);
    }

    for (int s = 0; s < SLABS; ++s) {
      ushort_t* cur = (s & 1) ? Xb : Xa;
      ushort_t* nxt = (s & 1) ? Xa : Xb;
      short8 v0 = z8, v1 = z8, v2 = z8, v3 = z8;
      const bool have_next = (s + 1 < SLABS);
      if (have_next) {
        const ushort_t* src = src_of(s + 1);
        if (src) { const short8* p = (const short8*)src; v0 = p[0]; v1 = p[1]; v2 = p[2]; v3 = p[3]; }
      }
      __builtin_amdgcn_s_setprio(1);
#pragma unroll
      for (int kb = 0; kb < 2; ++kb) {
        const int kbg = s * 2 + kb;
        short8 A[2], Bf[8];
#pragma unroll
        for (int mi = 0; mi < 2; ++mi)
          A[mi] = sw_load8(cur, mi * 16 + (lane & 15), 128, kb * 64 + (lane >> 4) * 16);
#pragma unroll
        for (int ni = 0; ni < 8; ++ni)
          Bf[ni] = *(const short8*)&W1f[(((size_t)kbg * 8 + ni) * 64 + lane) * 8];
#pragma unroll
        for (int mi = 0; mi < 2; ++mi)
#pragma unroll
          for (int ni = 0; ni < 8; ++ni)
            acc[mi][ni] = __builtin_amdgcn_mfma_f32_16x16x32_bf16(A[mi], Bf[ni], acc[mi][ni], 0, 0, 0);
      }
      __builtin_amdgcn_s_setprio(0);
      if (have_next) {
        sw_store8(nxt, sr, 128, shalf * 64 + 0, v0);
        sw_store8(nxt, sr, 128, shalf * 64 + 16, v1);
        sw_store8(nxt, sr, 128, shalf * 64 + 32, v2);
        sw_store8(nxt, sr, 128, shalf * 64 + 48, v3);
      }
    }
  }

  // Y1 = relu(acc) -> wave-private Y (overwrites X region; in-order LDS)
#pragma unroll
  for (int mi = 0; mi < 2; ++mi)
#pragma unroll
    for (int ni = 0; ni < 8; ++ni)
#pragma unroll
      for (int q = 0; q < 4; ++q) {
        const int row = mi * 16 + (lane >> 4) * 4 + q;
        const int col = ni * 16 + (lane & 15);
        sw_store1(Yw, row, 256, col, f2us(fmaxf(acc[mi][ni][q], 0.f)));
      }

  // ---- GEMM2 (A = own Y1) ----
#pragma unroll
  for (int ni = 0; ni < 8; ++ni) {
    const float bv = b2[ni * 16 + (lane & 15)];
#pragma unroll
    for (int mi = 0; mi < 2; ++mi) acc[mi][ni] = {bv, bv, bv, bv};
  }
  __builtin_amdgcn_s_setprio(1);
#pragma unroll
  for (int kb = 0; kb < 4; ++kb) {
    short8 A[2], Bf[8];
#pragma unroll
    for (int mi = 0; mi < 2; ++mi)
      A[mi] = sw_load8(Yw, mi * 16 + (lane & 15), 256, kb * 64 + (lane >> 4) * 16);
#pragma unroll
    for (int ni = 0; ni < 8; ++ni)
      Bf[ni] = *(const short8*)&W2f[(((size_t)kb * 8 + ni) * 64 + lane) * 8];
#pragma unroll
    for (int mi = 0; mi < 2; ++mi)
#pragma unroll
      for (int ni = 0; ni < 8; ++ni)
        acc[mi][ni] = __builtin_amdgcn_mfma_f32_16x16x32_bf16(A[mi], Bf[ni], acc[mi][ni], 0, 0, 0);
  }
  __builtin_amdgcn_s_setprio(0);
  // Y2 = relu(acc) over Y (reads above already completed in order)
#pragma unroll
  for (int mi = 0; mi < 2; ++mi)
#pragma unroll
    for (int ni = 0; ni < 8; ++ni)
#pragma unroll
      for (int q = 0; q < 4; ++q) {
        const int row = mi * 16 + (lane >> 4) * 4 + q;
        const int col = ni * 16 + (lane & 15);
        sw_store1(Yw, row, 256, col, f2us(fmaxf(acc[mi][ni][q], 0.f)));
      }

  // ---- GEMM3 (A = own Y2) ----
#pragma unroll
  for (int ni = 0; ni < 8; ++ni) {
    const float bv = b3[ni * 16 + (lane & 15)];
#pragma unroll
    for (int mi = 0; mi < 2; ++mi) acc[mi][ni] = {bv, bv, bv, bv};
  }
  __builtin_amdgcn_s_setprio(1);
#pragma unroll
  for (int kb = 0; kb < 4; ++kb) {
    short8 A[2], Bf[8];
#pragma unroll
    for (int mi = 0; mi < 2; ++mi)
      A[mi] = sw_load8(Yw, mi * 16 + (lane & 15), 256, kb * 64 + (lane >> 4) * 16);
#pragma unroll
    for (int ni = 0; ni < 8; ++ni)
      Bf[ni] = *(const short8*)&W3f[(((size_t)kb * 8 + ni) * 64 + lane) * 8];
#pragma unroll
    for (int mi = 0; mi < 2; ++mi)
#pragma unroll
      for (int ni = 0; ni < 8; ++ni)
        acc[mi][ni] = __builtin_amdgcn_mfma_f32_16x16x32_bf16(A[mi], Bf[ni], acc[mi][ni], 0, 0, 0);
  }
  __builtin_amdgcn_s_setprio(0);

  // ---- masked edge-sum (within wave: rows are this node's edges) ----
  float wrow[2][4];
#pragma unroll
  for (int mi = 0; mi < 2; ++mi)
#pragma unroll
    for (int q = 0; q < 4; ++q)
      wrow[mi][q] = s_watt[wid][mi * 16 + (lane >> 4) * 4 + q];
#pragma unroll
  for (int ni = 0; ni < 8; ++ni) {
    float p = 0.f;
#pragma unroll
    for (int q = 0; q < 4; ++q)
      p += wrow[0][q] * acc[0][ni][q] + wrow[1][q] * acc[1][ni][q];
    p += __shfl_xor(p, 16, 64);
    p += __shfl_xor(p, 32, 64);
    if (lane < 16) s_dh[wid][ni * 16 + lane] = p;
  }

  // ---- LN1 (this wave's node; in-order LDS read of s_dh) ----
  {
    const float x0 = us2f(hV_in[(size_t)node * HH + lane]) + s_dh[wid][lane] * (1.f / 30.f);
    const float x1 = us2f(hV_in[(size_t)node * HH + lane + 64]) + s_dh[wid][lane + 64] * (1.f / 30.f);
    float sm2 = x0 + x1;
#pragma unroll
    for (int m = 32; m >= 1; m >>= 1) sm2 += __shfl_xor(sm2, m, 64);
    const float mu = sm2 * (1.f / HH);
    const float d0 = x0 - mu, d1 = x1 - mu;
    float vv = d0 * d0 + d1 * d1;
#pragma unroll
    for (int m = 32; m >= 1; m >>= 1) vv += __shfl_xor(vv, m, 64);
    const float rs = rsqrtf(vv * (1.f / HH) + LEPS);
    h1out[(size_t)node * HH + lane] = f2us(g1[lane] * d0 * rs + bt1[lane]);
    h1out[(size_t)node * HH + lane + 64] = f2us(g1[lane + 64] * d1 * rs + bt1[lane + 64]);
  }
}

// ---------------- FF kernel: 32 rows/block; bf16 hV out ----------------
__global__ __launch_bounds__(256) void k_ff(
    const ushort_t* __restrict__ h1, const ushort_t* __restrict__ Winf,
    const ushort_t* __restrict__ Wfff,
    const float* __restrict__ bin, const float* __restrict__ bff,
    const float* __restrict__ g2, const float* __restrict__ bt2,
    const float* __restrict__ mask, ushort_t* __restrict__ hV_out)
{
  const int t = threadIdx.x, wid = t >> 6, lane = t & 63;
  const int row0 = blockIdx.x * 32;
  __shared__ alignas(16) ushort_t As[32 * 128];   // 8KB rowB=256
  __shared__ alignas(16) ushort_t Us[32 * 512];   // 32KB rowB=1024; reused as f32 h2

  {
    const int row = t >> 3, oct = t & 7;
    const short8* p = (const short8*)(h1 + (size_t)(row0 + row) * HH + oct * 16);
    sw_store8(As, row, 256, oct * 32, p[0]);
    sw_store8(As, row, 256, oct * 32 + 16, p[1]);
  }
  __syncthreads();

  // GEMM A: wave covers cols wid*128..+127 of N=512
  f32x4 ua[2][8];
#pragma unroll
  for (int ni = 0; ni < 8; ++ni) {
    const float bv = bin[wid * 128 + ni * 16 + (lane & 15)];
#pragma unroll
    for (int mi = 0; mi < 2; ++mi) ua[mi][ni] = {bv, bv, bv, bv};
  }
#pragma unroll
  for (int kb = 0; kb < 4; ++kb) {
    short8 A[2], Bf[8];
#pragma unroll
    for (int mi = 0; mi < 2; ++mi)
      A[mi] = sw_load8(As, mi * 16 + (lane & 15), 256, kb * 64 + (lane >> 4) * 16);
#pragma unroll
    for (int ni = 0; ni < 8; ++ni)
      Bf[ni] = *(const short8*)&Winf[(((size_t)kb * 32 + wid * 8 + ni) * 64 + lane) * 8];
#pragma unroll
    for (int mi = 0; mi < 2; ++mi)
#pragma unroll
      for (int ni = 0; ni < 8; ++ni)
        ua[mi][ni] = __builtin_amdgcn_mfma_f32_16x16x32_bf16(A[mi], Bf[ni], ua[mi][ni], 0, 0, 0);
  }
#pragma unroll
  for (int mi = 0; mi < 2; ++mi)
#pragma unroll
    for (int ni = 0; ni < 8; ++ni)
#pragma unroll
      for (int q = 0; q < 4; ++q) {
        const int row = mi * 16 + (lane >> 4) * 4 + q;
        const int col = wid * 128 + ni * 16 + (lane & 15);
        sw_store1(Us, row, 1024, col, f2us(fmaxf(ua[mi][ni][q], 0.f)));
      }
  __syncthreads();

  // GEMM B: wave covers cols wid*32..+31 of N=128; K=512
  f32x4 fa[2][2];
#pragma unroll
  for (int ni = 0; ni < 2; ++ni) {
    const float bv = bff[wid * 32 + ni * 16 + (lane & 15)];
#pragma unroll
    for (int mi = 0; mi < 2; ++mi) fa[mi][ni] = {bv, bv, bv, bv};
  }
#pragma unroll
  for (int kb = 0; kb < 16; ++kb) {
    short8 A[2], Bf[2];
#pragma unroll
    for (int mi = 0; mi < 2; ++mi)
      A[mi] = sw_load8(Us, mi * 16 + (lane & 15), 1024, kb * 64 + (lane >> 4) * 16);
#pragma unroll
    for (int ni = 0; ni < 2; ++ni)
      Bf[ni] = *(const short8*)&Wfff[(((size_t)kb * 8 + wid * 2 + ni) * 64 + lane) * 8];
#pragma unroll
    for (int mi = 0; mi < 2; ++mi)
#pragma unroll
      for (int ni = 0; ni < 2; ++ni)
        fa[mi][ni] = __builtin_amdgcn_mfma_f32_16x16x32_bf16(A[mi], Bf[ni], fa[mi][ni], 0, 0, 0);
  }
  __syncthreads();  // all reads of Us done

  float* h2 = (float*)Us;
#pragma unroll
  for (int mi = 0; mi < 2; ++mi)
#pragma unroll
    for (int ni = 0; ni < 2; ++ni)
#pragma unroll
      for (int q = 0; q < 4; ++q) {
        const int row = mi * 16 + (lane >> 4) * 4 + q;
        const int col = wid * 32 + ni * 16 + (lane & 15);
        h2[row * HH + col] = us2f(h1[(size_t)(row0 + row) * HH + col]) + fa[mi][ni][q];
      }
  __syncthreads();

  // LN2 + mask: 8 threads per row
  {
    const int row = t >> 3, oct = t & 7;
    float x[16], sm = 0.f;
#pragma unroll
    for (int i = 0; i < 16; ++i) { x[i] = h2[row * HH + oct * 16 + i]; sm += x[i]; }
    sm += __shfl_xor(sm, 1, 64); sm += __shfl_xor(sm, 2, 64); sm += __shfl_xor(sm, 4, 64);
    const float mu = sm * (1.f / HH);
    float vv = 0.f;
#pragma unroll
    for (int i = 0; i < 16; ++i) { const float d = x[i] - mu; vv += d * d; }
    vv += __shfl_xor(vv, 1, 64); vv += __shfl_xor(vv, 2, 64); vv += __shfl_xor(vv, 4, 64);
    const float rs = rsqrtf(vv * (1.f / HH) + LEPS);
    const float m1v = mask[row0 + row];
#pragma unroll
    for (int i = 0; i < 16; ++i) {
      const int col = oct * 16 + i;
      hV_out[(size_t)(row0 + row) * HH + col] =
          f2us((g2[col] * (x[i] - mu) * rs + bt2[col]) * m1v);
    }
  }
}

// ---------------- logits + log_softmax ----------------
__global__ __launch_bounds__(64) void k_out(
    const ushort_t* __restrict__ hV, const float* __restrict__ Wout,
    const float* __restrict__ bout, float* __restrict__ out)
{
  const int r = blockIdx.x;
  const int lane = threadIdx.x;
  __shared__ alignas(16) float sx[HH];
  sx[lane] = us2f(hV[(size_t)r * HH + lane]);
  sx[lane + 64] = us2f(hV[(size_t)r * HH + lane + 64]);
  __syncthreads();
  float logit = -1e30f;
  if (lane < NV) {
    float acc = bout[lane];
    for (int i = 0; i < HH; ++i) acc += sx[i] * Wout[i * NV + lane];
    logit = acc;
  }
  float mx = logit;
#pragma unroll
  for (int m = 32; m >= 1; m >>= 1) mx = fmaxf(mx, __shfl_xor(mx, m, 64));
  float e = (lane < NV) ? expf(logit - mx) : 0.f;
  float s = e;
#pragma unroll
  for (int m = 32; m >= 1; m >>= 1) s += __shfl_xor(s, m, 64);
  if (lane < NV) out[(size_t)r * NV + lane] = logit - mx - logf(s);
}

// ---------------- launcher ----------------
extern "C" void kernel_launch(void* const* d_in, const int* in_sizes, int n_in,
                              void* d_out, int out_size, void* d_ws, size_t ws_size,
                              hipStream_t stream)
{
  const int* S = (const int*)d_in[0];
  const float* V = (const float*)d_in[1];
  const float* E = (const float*)d_in[2];
  const int* E_idx = (const int*)d_in[3];
  const float* mask = (const float*)d_in[4];
  const float* Wv = (const float*)d_in[5];
  const float* bv = (const float*)d_in[6];
  const float* We = (const float*)d_in[7];
  const float* be = (const float*)d_in[8];
  const float* Wse = (const float*)d_in[9];
  const float* Wout = (const float*)d_in[10];
  const float* bout = (const float*)d_in[11];
  const float* eW[14];
  const float* dW[14];
  for (int i = 0; i < 14; ++i) eW[i] = (const float*)d_in[12 + i];
  for (int i = 0; i < 14; ++i) dW[i] = (const float*)d_in[26 + i];

  // ws layout (bytes):
  //   hE    bf16 : 62,914,560 @ 0
  //   hVa16 bf16 :  2,097,152 @ 62,914,560
  //   hVb16 bf16 :  2,097,152 @ 65,011,712
  //   h1    bf16 :  2,097,152 @ 67,108,864
  //   hS    bf16 :  2,097,152 @ 69,206,016
  //   WP    bf16 :  2,719,744 @ 71,303,168   (end 74,022,912)
  char* w = (char*)d_ws;
  ushort_t* hE = (ushort_t*)w;
  ushort_t* hVa = (ushort_t*)(w + 62914560u);
  ushort_t* hVb = (ushort_t*)(w + 65011712u);
  ushort_t* h1 = (ushort_t*)(w + 67108864u);
  ushort_t* hS = (ushort_t*)(w + 69206016u);
  ushort_t* WP = (ushort_t*)(w + 71303168u);

  const int R = 8 * NN;  // 8192

  // ---- build merged prep table (32 tensors) ----
  PrepTab tab;
  int ti = 0, blk = 0;
  auto addT = [&](const float* src, unsigned dstOff, int K, int nshift) {
    tab.src[ti] = src; tab.dstOff[ti] = dstOff;
    tab.blk0[ti] = blk; tab.nshift[ti] = nshift;
    blk += (K << nshift) >> 8;
    ++ti;
  };
  for (int l = 0; l < 3; ++l) {
    const unsigned base = l * 212992u;
    addT(eW[0] + l * 384 * 128, base + 0,      384, 7);
    addT(eW[2] + l * 128 * 128, base + 49152,  128, 7);
    addT(eW[4] + l * 128 * 128, base + 65536,  128, 7);
    addT(eW[6] + l * 128 * 512, base + 81920,  128, 9);
    addT(eW[8] + l * 512 * 128, base + 147456, 512, 7);
  }
  for (int l = 0; l < 3; ++l) {
    const unsigned base = 638976u + l * 229376u;
    addT(dW[0] + l * 512 * 128, base + 0,      512, 7);
    addT(dW[2] + l * 128 * 128, base + 65536,  128, 7);
    addT(dW[4] + l * 128 * 128, base + 81920,  128, 7);
    addT(dW[6] + l * 128 * 512, base + 98304,  128, 9);
    addT(dW[8] + l * 512 * 128, base + 163840, 512, 7);
  }
  addT(We, 1327104u, 128, 7);
  addT(Wv, 1343488u, 128, 7);
  k_prep_all<<<blk, 256, 0, stream>>>(tab, WP);  // blk == 5312

  // ---- embeddings ----
  k_gemm128<<<R / 128, 256, 0, stream>>>(V, WP + 1343488, bv, hVa);        // h_V (bf16)
  k_hs<<<R * 32 / 256, 256, 0, stream>>>(S, Wse, hS);                       // h_S
  k_gemm128<<<R * KNBR / 128, 256, 0, stream>>>(E, WP + 1327104, be, hE);  // h_E

  // encoder (in-place on hVa)
  for (int l = 0; l < 3; ++l) {
    const ushort_t* base = WP + l * 212992;
    k_msg<0><<<2048, 256, 0, stream>>>(hVa, hVa, hS, hE,
        base, base + 49152, base + 65536,
        eW[1] + l * 128, eW[3] + l * 128, eW[5] + l * 128,
        eW[10] + l * 128, eW[11] + l * 128, E_idx, mask, h1);
    k_ff<<<256, 256, 0, stream>>>(h1, base + 81920, base + 147456,
        eW[7] + l * 512, eW[9] + l * 128, eW[12] + l * 128, eW[13] + l * 128,
        mask, hVa);
  }
  // decoder: hV_enc = hVa (preserved); state rotates into hVb
  for (int l = 0; l < 3; ++l) {
    const ushort_t* base = WP + 638976 + l * 229376;
    const ushort_t* hin = (l == 0) ? hVa : hVb;
    k_msg<1><<<2048, 256, 0, stream>>>(hin, hVa, hS, hE,
        base, base + 65536, base + 81920,
        dW[1] + l * 128, dW[3] + l * 128, dW[5] + l * 128,
        dW[10] + l * 128, dW[11] + l * 128, E_idx, mask, h1);
    k_ff<<<256, 256, 0, stream>>>(h1, base + 98304, base + 163840,
        dW[7] + l * 512, dW[9] + l * 128, dW[12] + l * 128, dW[13] + l * 128,
        mask, hVb);
  }

  k_out<<<R, 64, 0, stream>>>(hVb, Wout, bout, (float*)d_out);

  (void)in_sizes; (void)n_in; (void)out_size; (void)ws_size;
}

// Round 11
// 557.606 us; speedup vs baseline: 1.0564x; 1.0564x over previous
//
#include <hip/hip_runtime.h>
#include <hip/hip_bf16.h>

#define HH 128
#define NN 1024
#define KNBR 30
#define NV 21
#define LEPS 1e-5f

typedef unsigned short ushort_t;
typedef __attribute__((ext_vector_type(8))) short short8;
typedef __attribute__((ext_vector_type(4))) short shortv4;
typedef __attribute__((ext_vector_type(4))) float f32x4;

__device__ __forceinline__ ushort_t f2us(float f) {
  __hip_bfloat16 h = __float2bfloat16(f);
  return __builtin_bit_cast(unsigned short, h);
}
__device__ __forceinline__ float us2f(ushort_t u) {
  __hip_bfloat16 h = __builtin_bit_cast(__hip_bfloat16, u);
  return __bfloat162float(h);
}

// XOR-swizzled LDS helpers (row-major, rowB bytes/row, swizzle within 128B)
__device__ __forceinline__ void sw_store8(ushort_t* base, int row, int rowB, int colByte, short8 v) {
  int byte = row * rowB + colByte;
  byte ^= (row & 7) << 4;
  *(short8*)((char*)base + byte) = v;
}
__device__ __forceinline__ short8 sw_load8(const ushort_t* base, int row, int rowB, int colByte) {
  int byte = row * rowB + colByte;
  byte ^= (row & 7) << 4;
  return *(const short8*)((const char*)base + byte);
}
__device__ __forceinline__ void sw_store1(ushort_t* base, int row, int rowB, int col, ushort_t v) {
  int byte = row * rowB + col * 2;
  byte ^= (row & 7) << 4;
  *(ushort_t*)((char*)base + byte) = v;
}

// ---------------- merged weight prep: 32 tensors in one launch ----------------
// frag idx: ((k>>5)*NT + (c>>4))*512 + (((k&31)>>3)*16 + (c&15))*8 + (k&7)
struct PrepTab {
  const float* src[32];
  unsigned dstOff[32];
  int blk0[32];     // starting block of each tensor (each block = 256 elems)
  int nshift[32];
};

__global__ __launch_bounds__(256) void k_prep_all(PrepTab tab, ushort_t* __restrict__ dst) {
  const int bid = blockIdx.x;
  int ti = 0;
#pragma unroll 1
  for (int i = 1; i < 32; ++i)
    if (bid >= tab.blk0[i]) ti = i;
  const int nshift = tab.nshift[ti];
  const int e = (bid - tab.blk0[ti]) * 256 + threadIdx.x;
  const int k = e >> nshift;
  const int c = e & ((1 << nshift) - 1);
  const int NT = 1 << (nshift - 4);
  const int idx = ((k >> 5) * NT + (c >> 4)) * 512 + (((k & 31) >> 3) * 16 + (c & 15)) * 8 + (k & 7);
  dst[tab.dstOff[ti] + idx] = f2us(tab.src[ti][e]);
}

// ---------------- 128x128x128 MFMA GEMM over row tiles, bf16 out ----------------
__global__ __launch_bounds__(256) void k_gemm128(
    const float* __restrict__ A, const ushort_t* __restrict__ Wf,
    const float* __restrict__ bias, ushort_t* __restrict__ out)
{
  const int t = threadIdx.x, wid = t >> 6, lane = t & 63;
  const int wm = wid >> 1, wn = wid & 1;
  const size_t row0 = (size_t)blockIdx.x * 128;
  __shared__ alignas(16) ushort_t Xs[128 * 128];  // 32KB, rowB=256

  // stage A tile (f32 -> bf16, swizzled): thread covers 64 floats = 8 x short8
  {
    const int row = t >> 1, half = t & 1;
    const float4* p = (const float4*)(A + (row0 + row) * HH + half * 64);
#pragma unroll
    for (int i = 0; i < 8; ++i) {
      short8 wv;
#pragma unroll
      for (int jj = 0; jj < 2; ++jj) {
        const float4 x = p[i * 2 + jj];
        wv[jj * 4 + 0] = (short)f2us(x.x);
        wv[jj * 4 + 1] = (short)f2us(x.y);
        wv[jj * 4 + 2] = (short)f2us(x.z);
        wv[jj * 4 + 3] = (short)f2us(x.w);
      }
      sw_store8(Xs, row, 256, half * 128 + i * 16, wv);
    }
  }
  __syncthreads();

  f32x4 acc[4][4];
#pragma unroll
  for (int ni = 0; ni < 4; ++ni) {
    const float bv = bias[wn * 64 + ni * 16 + (lane & 15)];
#pragma unroll
    for (int mi = 0; mi < 4; ++mi) acc[mi][ni] = {bv, bv, bv, bv};
  }
#pragma unroll
  for (int kb = 0; kb < 4; ++kb) {
    short8 Af[4], Bf[4];
#pragma unroll
    for (int mi = 0; mi < 4; ++mi)
      Af[mi] = sw_load8(Xs, wm * 64 + mi * 16 + (lane & 15), 256, kb * 64 + (lane >> 4) * 16);
#pragma unroll
    for (int ni = 0; ni < 4; ++ni)
      Bf[ni] = *(const short8*)&Wf[(((size_t)kb * 8 + wn * 4 + ni) * 64 + lane) * 8];
#pragma unroll
    for (int mi = 0; mi < 4; ++mi)
#pragma unroll
      for (int ni = 0; ni < 4; ++ni)
        acc[mi][ni] = __builtin_amdgcn_mfma_f32_16x16x32_bf16(Af[mi], Bf[ni], acc[mi][ni], 0, 0, 0);
  }

  __syncthreads();  // done reading Xs
#pragma unroll
  for (int mi = 0; mi < 4; ++mi)
#pragma unroll
    for (int ni = 0; ni < 4; ++ni)
#pragma unroll
      for (int q = 0; q < 4; ++q) {
        const int row = wm * 64 + mi * 16 + (lane >> 4) * 4 + q;
        const int col = wn * 64 + ni * 16 + (lane & 15);
        sw_store1(Xs, row, 256, col, f2us(acc[mi][ni][q]));
      }
  __syncthreads();
  {
    const int row = t >> 1, half = t & 1;
    ushort_t* o = out + (row0 + row) * HH + half * 64;
#pragma unroll
    for (int i = 0; i < 8; ++i)
      *(short8*)(o + i * 8) = sw_load8(Xs, row, 256, half * 128 + i * 16);
  }
}

// ---------------- h_S = Ws_emb[S] (bf16), vectorized gather ----------------
__global__ __launch_bounds__(256) void k_hs(
    const int* __restrict__ S, const float* __restrict__ Wse, ushort_t* __restrict__ hS)
{
  const int e = blockIdx.x * 256 + threadIdx.x;  // 4-elem groups, total 8192*32
  const int r = e >> 5, cq = e & 31;
  const float4 x = *(const float4*)(Wse + (size_t)S[r] * HH + cq * 4);
  shortv4 v;
  v[0] = (short)f2us(x.x); v[1] = (short)f2us(x.y);
  v[2] = (short)f2us(x.z); v[3] = (short)f2us(x.w);
  *(shortv4*)(hS + (size_t)r * HH + cq * 4) = v;
}

// ---------------- MFMA message kernel: 8 waves, 32x64 tile/wave ----------------
// Block = 512 threads = 8 waves in a 4x2 grid over the 128x128 output:
// wave (wr,wc) owns rows [wr*32,+32) x cols [wc*64,+64). acc = 2x4 f32x4 = 32
// regs -> total VGPR ~105 -> 4 waves/SIMD (double R9's occupancy).
// GEMM1 X double-buffered (loads issue before MFMA, stores after).
template <int DEC>
__global__ __launch_bounds__(512) void k_msg(
    const ushort_t* __restrict__ hV_in, const ushort_t* __restrict__ hV_enc,
    const ushort_t* __restrict__ hS, const ushort_t* __restrict__ hE,
    const ushort_t* __restrict__ W1f, const ushort_t* __restrict__ W2f,
    const ushort_t* __restrict__ W3f,
    const float* __restrict__ b1, const float* __restrict__ b2,
    const float* __restrict__ b3,
    const float* __restrict__ g1, const float* __restrict__ bt1,
    const int* __restrict__ E_idx, const float* __restrict__ mask,
    ushort_t* __restrict__ h1out)
{
  constexpr int INF = DEC ? 4 * HH : 3 * HH;
  constexpr int SLABS = INF / 64;
  const int t = threadIdx.x;
  const int wid = t >> 6, lane = t & 63;
  const int wr = wid >> 1, wc = wid & 1;
  const int node0 = blockIdx.x * 4;
  const int bb = node0 >> 10;
  const int np0 = node0 & (NN - 1);

  __shared__ alignas(16) ushort_t U[128 * 128];  // 32KB union: {Xa|Xb} | Ys
  __shared__ int s_nb[128];
  __shared__ float s_watt[128];
  __shared__ signed char s_ar[128];
  __shared__ float dhs[4][128];                  // 2KB, separate (no union hazard)
  ushort_t* Xa = U;                 // [128][64] rowB=128 (16KB)
  ushort_t* Xb = U + 128 * 64;      // 16KB
  ushort_t* Ys = U;                 // [128][128] rowB=256 after GEMM1

  if (t < 128) {
    const int g = t >> 5, e = t & 31;
    const int r = node0 + g;
    int nb = 0, arI = 0;
    float watt = 0.f;
    if (e < KNBR) {
      nb = E_idx[(size_t)r * KNBR + e];
      if (DEC) {
        arI = (nb < np0 + g) ? 1 : 0;
        watt = 1.f;
      } else {
        watt = mask[r] * mask[bb * NN + nb];
      }
    }
    s_nb[t] = nb; s_watt[t] = watt; s_ar[t] = (signed char)arI;
  }
  __syncthreads();

  // staging geometry: 512 threads, row sr = t>>2, quarter sq = t&3 (16 elems = 32B)
  const int sr = t >> 2, sq = t & 3;
  const int sg = sr >> 5, se = sr & 31;
  const bool srv = (se < KNBR);
  const int snb = s_nb[sr];
  const bool sar = (bool)s_ar[sr];

  auto src_of = [&](int s) -> const ushort_t* {
    if (!srv) return nullptr;
    const int fc0 = s * 64 + sq * 16;
    const int seg = fc0 >> 7, off = fc0 & 127;
    if (seg == 0) return hV_in + (size_t)(node0 + sg) * HH + off;
    if (seg == 1) return hE + ((size_t)(node0 + sg) * KNBR + se) * HH + off;
    if (seg == 2) {
      if (DEC) return sar ? (hS + (size_t)(bb * NN + snb) * HH + off) : nullptr;
      return hV_in + (size_t)(bb * NN + snb) * HH + off;
    }
    return (sar ? hV_in : hV_enc) + (size_t)(bb * NN + snb) * HH + off;
  };

  f32x4 acc[2][4];
#pragma unroll
  for (int ni = 0; ni < 4; ++ni) {
    const float bv = b1[wc * 64 + ni * 16 + (lane & 15)];
#pragma unroll
    for (int mi = 0; mi < 2; ++mi) acc[mi][ni] = {bv, bv, bv, bv};
  }

  // ---- GEMM1: double-buffered slabs, one barrier per slab ----
  {
    const short8 z8 = {0, 0, 0, 0, 0, 0, 0, 0};
    {
      const ushort_t* src = src_of(0);
      short8 v0 = z8, v1 = z8;
      if (src) { const short8* p = (const short8*)src; v0 = p[0]; v1 = p[1]; }
      sw_store8(Xa, sr, 128, sq * 32, v0);
      sw_store8(Xa, sr, 128, sq * 32 + 16, v1);
    }
    __syncthreads();

    for (int s = 0; s < SLABS; ++s) {
      ushort_t* cur = (s & 1) ? Xb : Xa;
      ushort_t* nxt = (s & 1) ? Xa : Xb;
      short8 v0 = {0, 0, 0, 0, 0, 0, 0, 0}, v1 = v0;
      const bool have_next = (s + 1 < SLABS);
      if (have_next) {
        const ushort_t* src = src_of(s + 1);
        if (src) { const short8* p = (const short8*)src; v0 = p[0]; v1 = p[1]; }
      }
#pragma unroll
      for (int kb = 0; kb < 2; ++kb) {
        const int kbg = s * 2 + kb;
        short8 A[2], Bf[4];
#pragma unroll
        for (int mi = 0; mi < 2; ++mi)
          A[mi] = sw_load8(cur, wr * 32 + mi * 16 + (lane & 15), 128, kb * 64 + (lane >> 4) * 16);
#pragma unroll
        for (int ni = 0; ni < 4; ++ni)
          Bf[ni] = *(const short8*)&W1f[(((size_t)kbg * 8 + wc * 4 + ni) * 64 + lane) * 8];
#pragma unroll
        for (int mi = 0; mi < 2; ++mi)
#pragma unroll
          for (int ni = 0; ni < 4; ++ni)
            acc[mi][ni] = __builtin_amdgcn_mfma_f32_16x16x32_bf16(A[mi], Bf[ni], acc[mi][ni], 0, 0, 0);
      }
      if (have_next) {
        sw_store8(nxt, sr, 128, sq * 32, v0);
        sw_store8(nxt, sr, 128, sq * 32 + 16, v1);
      }
      __syncthreads();
    }
  }

  // Y1 = relu(acc) (X buffers dead after final barrier)
#pragma unroll
  for (int mi = 0; mi < 2; ++mi)
#pragma unroll
    for (int ni = 0; ni < 4; ++ni)
#pragma unroll
      for (int q = 0; q < 4; ++q) {
        const int row = wr * 32 + mi * 16 + (lane >> 4) * 4 + q;
        const int col = wc * 64 + ni * 16 + (lane & 15);
        sw_store1(Ys, row, 256, col, f2us(fmaxf(acc[mi][ni][q], 0.f)));
      }
  __syncthreads();

  // ---- GEMM2 ----
#pragma unroll
  for (int ni = 0; ni < 4; ++ni) {
    const float bv = b2[wc * 64 + ni * 16 + (lane & 15)];
#pragma unroll
    for (int mi = 0; mi < 2; ++mi) acc[mi][ni] = {bv, bv, bv, bv};
  }
#pragma unroll
  for (int kb = 0; kb < 4; ++kb) {
    short8 A[2], Bf[4];
#pragma unroll
    for (int mi = 0; mi < 2; ++mi)
      A[mi] = sw_load8(Ys, wr * 32 + mi * 16 + (lane & 15), 256, kb * 64 + (lane >> 4) * 16);
#pragma unroll
    for (int ni = 0; ni < 4; ++ni)
      Bf[ni] = *(const short8*)&W2f[(((size_t)kb * 8 + wc * 4 + ni) * 64 + lane) * 8];
#pragma unroll
    for (int mi = 0; mi < 2; ++mi)
#pragma unroll
      for (int ni = 0; ni < 4; ++ni)
        acc[mi][ni] = __builtin_amdgcn_mfma_f32_16x16x32_bf16(A[mi], Bf[ni], acc[mi][ni], 0, 0, 0);
  }
  __syncthreads();
#pragma unroll
  for (int mi = 0; mi < 2; ++mi)
#pragma unroll
    for (int ni = 0; ni < 4; ++ni)
#pragma unroll
      for (int q = 0; q < 4; ++q) {
        const int row = wr * 32 + mi * 16 + (lane >> 4) * 4 + q;
        const int col = wc * 64 + ni * 16 + (lane & 15);
        sw_store1(Ys, row, 256, col, f2us(fmaxf(acc[mi][ni][q], 0.f)));
      }
  __syncthreads();

  // ---- GEMM3 ----
#pragma unroll
  for (int ni = 0; ni < 4; ++ni) {
    const float bv = b3[wc * 64 + ni * 16 + (lane & 15)];
#pragma unroll
    for (int mi = 0; mi < 2; ++mi) acc[mi][ni] = {bv, bv, bv, bv};
  }
#pragma unroll
  for (int kb = 0; kb < 4; ++kb) {
    short8 A[2], Bf[4];
#pragma unroll
    for (int mi = 0; mi < 2; ++mi)
      A[mi] = sw_load8(Ys, wr * 32 + mi * 16 + (lane & 15), 256, kb * 64 + (lane >> 4) * 16);
#pragma unroll
    for (int ni = 0; ni < 4; ++ni)
      Bf[ni] = *(const short8*)&W3f[(((size_t)kb * 8 + wc * 4 + ni) * 64 + lane) * 8];
#pragma unroll
    for (int mi = 0; mi < 2; ++mi)
#pragma unroll
      for (int ni = 0; ni < 4; ++ni)
        acc[mi][ni] = __builtin_amdgcn_mfma_f32_16x16x32_bf16(A[mi], Bf[ni], acc[mi][ni], 0, 0, 0);
  }

  // ---- masked edge-sum -> dh (wave rows = node wr's 32 edge slots) ----
  float wrow[2][4];
#pragma unroll
  for (int mi = 0; mi < 2; ++mi)
#pragma unroll
    for (int q = 0; q < 4; ++q)
      wrow[mi][q] = s_watt[wr * 32 + mi * 16 + (lane >> 4) * 4 + q];
#pragma unroll
  for (int ni = 0; ni < 4; ++ni) {
    float p = 0.f;
#pragma unroll
    for (int q = 0; q < 4; ++q)
      p += wrow[0][q] * acc[0][ni][q] + wrow[1][q] * acc[1][ni][q];
    p += __shfl_xor(p, 16, 64);
    p += __shfl_xor(p, 32, 64);
    if (lane < 16) dhs[wr][wc * 64 + ni * 16 + lane] = p;
  }
  __syncthreads();

  // ---- LN1: waves 0..3 handle node0+wid ----
  if (wid < 4) {
    const int r = node0 + wid;
    const float x0 = us2f(hV_in[(size_t)r * HH + lane]) + dhs[wid][lane] * (1.f / 30.f);
    const float x1 = us2f(hV_in[(size_t)r * HH + lane + 64]) + dhs[wid][lane + 64] * (1.f / 30.f);
    float sm2 = x0 + x1;
#pragma unroll
    for (int m = 32; m >= 1; m >>= 1) sm2 += __shfl_xor(sm2, m, 64);
    const float mu = sm2 * (1.f / HH);
    const float d0 = x0 - mu, d1 = x1 - mu;
    float vv = d0 * d0 + d1 * d1;
#pragma unroll
    for (int m = 32; m >= 1; m >>= 1) vv += __shfl_xor(vv, m, 64);
    const float rs = rsqrtf(vv * (1.f / HH) + LEPS);
    h1out[(size_t)r * HH + lane] = f2us(g1[lane] * d0 * rs + bt1[lane]);
    h1out[(size_t)r * HH + lane + 64] = f2us(g1[lane + 64] * d1 * rs + bt1[lane + 64]);
  }
}

// ---------------- FF kernel: 32 rows/block; bf16 hV out ----------------
__global__ __launch_bounds__(256) void k_ff(
    const ushort_t* __restrict__ h1, const ushort_t* __restrict__ Winf,
    const ushort_t* __restrict__ Wfff,
    const float* __restrict__ bin, const float* __restrict__ bff,
    const float* __restrict__ g2, const float* __restrict__ bt2,
    const float* __restrict__ mask, ushort_t* __restrict__ hV_out)
{
  const int t = threadIdx.x, wid = t >> 6, lane = t & 63;
  const int row0 = blockIdx.x * 32;
  __shared__ alignas(16) ushort_t As[32 * 128];   // 8KB rowB=256
  __shared__ alignas(16) ushort_t Us[32 * 512];   // 32KB rowB=1024; reused as f32 h2

  {
    const int row = t >> 3, oct = t & 7;
    const short8* p = (const short8*)(h1 + (size_t)(row0 + row) * HH + oct * 16);
    sw_store8(As, row, 256, oct * 32, p[0]);
    sw_store8(As, row, 256, oct * 32 + 16, p[1]);
  }
  __syncthreads();

  // GEMM A: wave covers cols wid*128..+127 of N=512
  f32x4 ua[2][8];
#pragma unroll
  for (int ni = 0; ni < 8; ++ni) {
    const float bv = bin[wid * 128 + ni * 16 + (lane & 15)];
#pragma unroll
    for (int mi = 0; mi < 2; ++mi) ua[mi][ni] = {bv, bv, bv, bv};
  }
#pragma unroll
  for (int kb = 0; kb < 4; ++kb) {
    short8 A[2], Bf[8];
#pragma unroll
    for (int mi = 0; mi < 2; ++mi)
      A[mi] = sw_load8(As, mi * 16 + (lane & 15), 256, kb * 64 + (lane >> 4) * 16);
#pragma unroll
    for (int ni = 0; ni < 8; ++ni)
      Bf[ni] = *(const short8*)&Winf[(((size_t)kb * 32 + wid * 8 + ni) * 64 + lane) * 8];
#pragma unroll
    for (int mi = 0; mi < 2; ++mi)
#pragma unroll
      for (int ni = 0; ni < 8; ++ni)
        ua[mi][ni] = __builtin_amdgcn_mfma_f32_16x16x32_bf16(A[mi], Bf[ni], ua[mi][ni], 0, 0, 0);
  }
#pragma unroll
  for (int mi = 0; mi < 2; ++mi)
#pragma unroll
    for (int ni = 0; ni < 8; ++ni)
#pragma unroll
      for (int q = 0; q < 4; ++q) {
        const int row = mi * 16 + (lane >> 4) * 4 + q;
        const int col = wid * 128 + ni * 16 + (lane & 15);
        sw_store1(Us, row, 1024, col, f2us(fmaxf(ua[mi][ni][q], 0.f)));
      }
  __syncthreads();

  // GEMM B: wave covers cols wid*32..+31 of N=128; K=512
  f32x4 fa[2][2];
#pragma unroll
  for (int ni = 0; ni < 2; ++ni) {
    const float bv = bff[wid * 32 + ni * 16 + (lane & 15)];
#pragma unroll
    for (int mi = 0; mi < 2; ++mi) fa[mi][ni] = {bv, bv, bv, bv};
  }
#pragma unroll
  for (int kb = 0; kb < 16; ++kb) {
    short8 A[2], Bf[2];
#pragma unroll
    for (int mi = 0; mi < 2; ++mi)
      A[mi] = sw_load8(Us, mi * 16 + (lane & 15), 1024, kb * 64 + (lane >> 4) * 16);
#pragma unroll
    for (int ni = 0; ni < 2; ++ni)
      Bf[ni] = *(const short8*)&Wfff[(((size_t)kb * 8 + wid * 2 + ni) * 64 + lane) * 8];
#pragma unroll
    for (int mi = 0; mi < 2; ++mi)
#pragma unroll
      for (int ni = 0; ni < 2; ++ni)
        fa[mi][ni] = __builtin_amdgcn_mfma_f32_16x16x32_bf16(A[mi], Bf[ni], fa[mi][ni], 0, 0, 0);
  }
  __syncthreads();  // all reads of Us done

  float* h2 = (float*)Us;
#pragma unroll
  for (int mi = 0; mi < 2; ++mi)
#pragma unroll
    for (int ni = 0; ni < 2; ++ni)
#pragma unroll
      for (int q = 0; q < 4; ++q) {
        const int row = mi * 16 + (lane >> 4) * 4 + q;
        const int col = wid * 32 + ni * 16 + (lane & 15);
        h2[row * HH + col] = us2f(h1[(size_t)(row0 + row) * HH + col]) + fa[mi][ni][q];
      }
  __syncthreads();

  // LN2 + mask: 8 threads per row
  {
    const int row = t >> 3, oct = t & 7;
    float x[16], sm = 0.f;
#pragma unroll
    for (int i = 0; i < 16; ++i) { x[i] = h2[row * HH + oct * 16 + i]; sm += x[i]; }
    sm += __shfl_xor(sm, 1, 64); sm += __shfl_xor(sm, 2, 64); sm += __shfl_xor(sm, 4, 64);
    const float mu = sm * (1.f / HH);
    float vv = 0.f;
#pragma unroll
    for (int i = 0; i < 16; ++i) { const float d = x[i] - mu; vv += d * d; }
    vv += __shfl_xor(vv, 1, 64); vv += __shfl_xor(vv, 2, 64); vv += __shfl_xor(vv, 4, 64);
    const float rs = rsqrtf(vv * (1.f / HH) + LEPS);
    const float m1v = mask[row0 + row];
#pragma unroll
    for (int i = 0; i < 16; ++i) {
      const int col = oct * 16 + i;
      hV_out[(size_t)(row0 + row) * HH + col] =
          f2us((g2[col] * (x[i] - mu) * rs + bt2[col]) * m1v);
    }
  }
}

// ---------------- logits + log_softmax ----------------
__global__ __launch_bounds__(64) void k_out(
    const ushort_t* __restrict__ hV, const float* __restrict__ Wout,
    const float* __restrict__ bout, float* __restrict__ out)
{
  const int r = blockIdx.x;
  const int lane = threadIdx.x;
  __shared__ alignas(16) float sx[HH];
  sx[lane] = us2f(hV[(size_t)r * HH + lane]);
  sx[lane + 64] = us2f(hV[(size_t)r * HH + lane + 64]);
  __syncthreads();
  float logit = -1e30f;
  if (lane < NV) {
    float acc = bout[lane];
    for (int i = 0; i < HH; ++i) acc += sx[i] * Wout[i * NV + lane];
    logit = acc;
  }
  float mx = logit;
#pragma unroll
  for (int m = 32; m >= 1; m >>= 1) mx = fmaxf(mx, __shfl_xor(mx, m, 64));
  float e = (lane < NV) ? expf(logit - mx) : 0.f;
  float s = e;
#pragma unroll
  for (int m = 32; m >= 1; m >>= 1) s += __shfl_xor(s, m, 64);
  if (lane < NV) out[(size_t)r * NV + lane] = logit - mx - logf(s);
}

// ---------------- launcher ----------------
extern "C" void kernel_launch(void* const* d_in, const int* in_sizes, int n_in,
                              void* d_out, int out_size, void* d_ws, size_t ws_size,
                              hipStream_t stream)
{
  const int* S = (const int*)d_in[0];
  const float* V = (const float*)d_in[1];
  const float* E = (const float*)d_in[2];
  const int* E_idx = (const int*)d_in[3];
  const float* mask = (const float*)d_in[4];
  const float* Wv = (const float*)d_in[5];
  const float* bv = (const float*)d_in[6];
  const float* We = (const float*)d_in[7];
  const float* be = (const float*)d_in[8];
  const float* Wse = (const float*)d_in[9];
  const float* Wout = (const float*)d_in[10];
  const float* bout = (const float*)d_in[11];
  const float* eW[14];
  const float* dW[14];
  for (int i = 0; i < 14; ++i) eW[i] = (const float*)d_in[12 + i];
  for (int i = 0; i < 14; ++i) dW[i] = (const float*)d_in[26 + i];

  // ws layout (bytes):
  //   hE    bf16 : 62,914,560 @ 0
  //   hVa16 bf16 :  2,097,152 @ 62,914,560
  //   hVb16 bf16 :  2,097,152 @ 65,011,712
  //   h1    bf16 :  2,097,152 @ 67,108,864
  //   hS    bf16 :  2,097,152 @ 69,206,016
  //   WP    bf16 :  2,719,744 @ 71,303,168   (end 74,022,912)
  char* w = (char*)d_ws;
  ushort_t* hE = (ushort_t*)w;
  ushort_t* hVa = (ushort_t*)(w + 62914560u);
  ushort_t* hVb = (ushort_t*)(w + 65011712u);
  ushort_t* h1 = (ushort_t*)(w + 67108864u);
  ushort_t* hS = (ushort_t*)(w + 69206016u);
  ushort_t* WP = (ushort_t*)(w + 71303168u);

  const int R = 8 * NN;  // 8192

  // ---- build merged prep table (32 tensors) ----
  PrepTab tab;
  int ti = 0, blk = 0;
  auto addT = [&](const float* src, unsigned dstOff, int K, int nshift) {
    tab.src[ti] = src; tab.dstOff[ti] = dstOff;
    tab.blk0[ti] = blk; tab.nshift[ti] = nshift;
    blk += (K << nshift) >> 8;
    ++ti;
  };
  for (int l = 0; l < 3; ++l) {
    const unsigned base = l * 212992u;
    addT(eW[0] + l * 384 * 128, base + 0,      384, 7);
    addT(eW[2] + l * 128 * 128, base + 49152,  128, 7);
    addT(eW[4] + l * 128 * 128, base + 65536,  128, 7);
    addT(eW[6] + l * 128 * 512, base + 81920,  128, 9);
    addT(eW[8] + l * 512 * 128, base + 147456, 512, 7);
  }
  for (int l = 0; l < 3; ++l) {
    const unsigned base = 638976u + l * 229376u;
    addT(dW[0] + l * 512 * 128, base + 0,      512, 7);
    addT(dW[2] + l * 128 * 128, base + 65536,  128, 7);
    addT(dW[4] + l * 128 * 128, base + 81920,  128, 7);
    addT(dW[6] + l * 128 * 512, base + 98304,  128, 9);
    addT(dW[8] + l * 512 * 128, base + 163840, 512, 7);
  }
  addT(We, 1327104u, 128, 7);
  addT(Wv, 1343488u, 128, 7);
  k_prep_all<<<blk, 256, 0, stream>>>(tab, WP);  // blk == 5312

  // ---- embeddings ----
  k_gemm128<<<R / 128, 256, 0, stream>>>(V, WP + 1343488, bv, hVa);        // h_V (bf16)
  k_hs<<<R * 32 / 256, 256, 0, stream>>>(S, Wse, hS);                       // h_S
  k_gemm128<<<R * KNBR / 128, 256, 0, stream>>>(E, WP + 1327104, be, hE);  // h_E

  // encoder (in-place on hVa)
  for (int l = 0; l < 3; ++l) {
    const ushort_t* base = WP + l * 212992;
    k_msg<0><<<2048, 512, 0, stream>>>(hVa, hVa, hS, hE,
        base, base + 49152, base + 65536,
        eW[1] + l * 128, eW[3] + l * 128, eW[5] + l * 128,
        eW[10] + l * 128, eW[11] + l * 128, E_idx, mask, h1);
    k_ff<<<256, 256, 0, stream>>>(h1, base + 81920, base + 147456,
        eW[7] + l * 512, eW[9] + l * 128, eW[12] + l * 128, eW[13] + l * 128,
        mask, hVa);
  }
  // decoder: hV_enc = hVa (preserved); state rotates into hVb
  for (int l = 0; l < 3; ++l) {
    const ushort_t* base = WP + 638976 + l * 229376;
    const ushort_t* hin = (l == 0) ? hVa : hVb;
    k_msg<1><<<2048, 512, 0, stream>>>(hin, hVa, hS, hE,
        base, base + 65536, base + 81920,
        dW[1] + l * 128, dW[3] + l * 128, dW[5] + l * 128,
        dW[10] + l * 128, dW[11] + l * 128, E_idx, mask, h1);
    k_ff<<<256, 256, 0, stream>>>(h1, base + 98304, base + 163840,
        dW[7] + l * 512, dW[9] + l * 128, dW[12] + l * 128, dW[13] + l * 128,
        mask, hVb);
  }

  k_out<<<R, 64, 0, stream>>>(hVb, Wout, bout, (float*)d_out);

  (void)in_sizes; (void)n_in; (void)out_size; (void)ws_size;
}

// Round 12
// 530.451 us; speedup vs baseline: 1.1105x; 1.0512x over previous
//
#include <hip/hip_runtime.h>
#include <hip/hip_bf16.h>

#define HH 128
#define NN 1024
#define KNBR 30
#define NV 21
#define LEPS 1e-5f

typedef unsigned short ushort_t;
typedef __attribute__((ext_vector_type(8))) short short8;
typedef __attribute__((ext_vector_type(4))) short shortv4;
typedef __attribute__((ext_vector_type(4))) float f32x4;

__device__ __forceinline__ ushort_t f2us(float f) {
  __hip_bfloat16 h = __float2bfloat16(f);
  return __builtin_bit_cast(unsigned short, h);
}
__device__ __forceinline__ float us2f(ushort_t u) {
  __hip_bfloat16 h = __builtin_bit_cast(__hip_bfloat16, u);
  return __bfloat162float(h);
}

// XOR-swizzled LDS helpers (row-major, rowB bytes/row, swizzle within 128B)
__device__ __forceinline__ void sw_store8(ushort_t* base, int row, int rowB, int colByte, short8 v) {
  int byte = row * rowB + colByte;
  byte ^= (row & 7) << 4;
  *(short8*)((char*)base + byte) = v;
}
__device__ __forceinline__ short8 sw_load8(const ushort_t* base, int row, int rowB, int colByte) {
  int byte = row * rowB + colByte;
  byte ^= (row & 7) << 4;
  return *(const short8*)((const char*)base + byte);
}
__device__ __forceinline__ void sw_store1(ushort_t* base, int row, int rowB, int col, ushort_t v) {
  int byte = row * rowB + col * 2;
  byte ^= (row & 7) << 4;
  *(ushort_t*)((char*)base + byte) = v;
}

// ---------------- merged weight prep: 32 tensors in one launch ----------------
// frag idx: ((k>>5)*NT + (c>>4))*512 + (((k&31)>>3)*16 + (c&15))*8 + (k&7)
struct PrepTab {
  const float* src[32];
  unsigned dstOff[32];
  int blk0[32];     // starting block of each tensor (each block = 256 elems)
  int nshift[32];
};

__global__ __launch_bounds__(256) void k_prep_all(PrepTab tab, ushort_t* __restrict__ dst) {
  const int bid = blockIdx.x;
  int ti = 0;
#pragma unroll 1
  for (int i = 1; i < 32; ++i)
    if (bid >= tab.blk0[i]) ti = i;
  const int nshift = tab.nshift[ti];
  const int e = (bid - tab.blk0[ti]) * 256 + threadIdx.x;
  const int k = e >> nshift;
  const int c = e & ((1 << nshift) - 1);
  const int NT = 1 << (nshift - 4);
  const int idx = ((k >> 5) * NT + (c >> 4)) * 512 + (((k & 31) >> 3) * 16 + (c & 15)) * 8 + (k & 7);
  dst[tab.dstOff[ti] + idx] = f2us(tab.src[ti][e]);
}

// ---------------- 64x128x128 MFMA GEMM over row tiles, bf16 out ----------------
// 64-row tiles: 16KB LDS -> many blocks/CU so the serial per-block chain
// (load -> cvt -> LDS -> MFMA -> LDS -> store) pipelines across blocks.
__global__ __launch_bounds__(256) void k_gemm64(
    const float* __restrict__ A, const ushort_t* __restrict__ Wf,
    const float* __restrict__ bias, ushort_t* __restrict__ out)
{
  const int t = threadIdx.x, wid = t >> 6, lane = t & 63;
  const int wm = wid >> 1, wn = wid & 1;
  const size_t row0 = (size_t)blockIdx.x * 64;
  __shared__ alignas(16) ushort_t Xs[64 * 128];  // 16KB, rowB=256

  // stage A tile (f32 -> bf16, swizzled): thread covers 32 floats = 4 x short8
  {
    const int row = t >> 2, q = t & 3;
    const float4* p = (const float4*)(A + (row0 + row) * HH + q * 32);
#pragma unroll
    for (int i = 0; i < 4; ++i) {
      short8 wv;
#pragma unroll
      for (int jj = 0; jj < 2; ++jj) {
        const float4 x = p[i * 2 + jj];
        wv[jj * 4 + 0] = (short)f2us(x.x);
        wv[jj * 4 + 1] = (short)f2us(x.y);
        wv[jj * 4 + 2] = (short)f2us(x.z);
        wv[jj * 4 + 3] = (short)f2us(x.w);
      }
      sw_store8(Xs, row, 256, q * 64 + i * 16, wv);
    }
  }
  __syncthreads();

  f32x4 acc[2][4];
#pragma unroll
  for (int ni = 0; ni < 4; ++ni) {
    const float bv = bias[wn * 64 + ni * 16 + (lane & 15)];
#pragma unroll
    for (int mi = 0; mi < 2; ++mi) acc[mi][ni] = {bv, bv, bv, bv};
  }
#pragma unroll
  for (int kb = 0; kb < 4; ++kb) {
    short8 Af[2], Bf[4];
#pragma unroll
    for (int mi = 0; mi < 2; ++mi)
      Af[mi] = sw_load8(Xs, wm * 32 + mi * 16 + (lane & 15), 256, kb * 64 + (lane >> 4) * 16);
#pragma unroll
    for (int ni = 0; ni < 4; ++ni)
      Bf[ni] = *(const short8*)&Wf[(((size_t)kb * 8 + wn * 4 + ni) * 64 + lane) * 8];
#pragma unroll
    for (int mi = 0; mi < 2; ++mi)
#pragma unroll
      for (int ni = 0; ni < 4; ++ni)
        acc[mi][ni] = __builtin_amdgcn_mfma_f32_16x16x32_bf16(Af[mi], Bf[ni], acc[mi][ni], 0, 0, 0);
  }

  __syncthreads();  // done reading Xs
#pragma unroll
  for (int mi = 0; mi < 2; ++mi)
#pragma unroll
    for (int ni = 0; ni < 4; ++ni)
#pragma unroll
      for (int q = 0; q < 4; ++q) {
        const int row = wm * 32 + mi * 16 + (lane >> 4) * 4 + q;
        const int col = wn * 64 + ni * 16 + (lane & 15);
        sw_store1(Xs, row, 256, col, f2us(acc[mi][ni][q]));
      }
  __syncthreads();
  {
    const int row = t >> 2, q = t & 3;
    ushort_t* o = out + (row0 + row) * HH + q * 32;
#pragma unroll
    for (int i = 0; i < 4; ++i)
      *(short8*)(o + i * 8) = sw_load8(Xs, row, 256, q * 64 + i * 16);
  }
}

// ---------------- h_S = Ws_emb[S] (bf16), vectorized gather ----------------
__global__ __launch_bounds__(256) void k_hs(
    const int* __restrict__ S, const float* __restrict__ Wse, ushort_t* __restrict__ hS)
{
  const int e = blockIdx.x * 256 + threadIdx.x;  // 4-elem groups, total 8192*32
  const int r = e >> 5, cq = e & 31;
  const float4 x = *(const float4*)(Wse + (size_t)S[r] * HH + cq * 4);
  shortv4 v;
  v[0] = (short)f2us(x.x); v[1] = (short)f2us(x.y);
  v[2] = (short)f2us(x.z); v[3] = (short)f2us(x.w);
  *(shortv4*)(hS + (size_t)r * HH + cq * 4) = v;
}

// ---------------- MFMA message kernel: 4 nodes/block, M=128, 4 waves ----------------
// GEMM1 X double-buffered with 2-DEEP register prefetch: loads for slab s+2
// issue at iter s, land in LDS at end of iter s+1 -> ~2 MFMA phases of latency
// cover (vs 1 phase for the 1-deep pipeline).
template <int DEC>
__global__ __launch_bounds__(256) void k_msg(
    const ushort_t* __restrict__ hV_in, const ushort_t* __restrict__ hV_enc,
    const ushort_t* __restrict__ hS, const ushort_t* __restrict__ hE,
    const ushort_t* __restrict__ W1f, const ushort_t* __restrict__ W2f,
    const ushort_t* __restrict__ W3f,
    const float* __restrict__ b1, const float* __restrict__ b2,
    const float* __restrict__ b3,
    const float* __restrict__ g1, const float* __restrict__ bt1,
    const int* __restrict__ E_idx, const float* __restrict__ mask,
    ushort_t* __restrict__ h1out)
{
  constexpr int INF = DEC ? 4 * HH : 3 * HH;
  constexpr int SLABS = INF / 64;
  const int t = threadIdx.x;
  const int wid = t >> 6, lane = t & 63;
  const int wm = wid >> 1, wn = wid & 1;
  const int node0 = blockIdx.x * 4;
  const int bb = node0 >> 10;
  const int np0 = node0 & (NN - 1);

  __shared__ alignas(16) ushort_t U[128 * 128];  // 32KB union: {Xa|Xb} | Ys | dhs
  __shared__ int s_nb[128];
  __shared__ float s_watt[128];
  __shared__ signed char s_ar[128];
  ushort_t* Xa = U;                 // [128][64] rowB=128 (16KB)
  ushort_t* Xb = U + 128 * 64;      // 16KB
  ushort_t* Ys = U;                 // [128][128] rowB=256 after GEMM1
  float* dhs = (float*)U;           // [4][HH] after GEMM3

  if (t < 128) {
    const int g = t >> 5, e = t & 31;
    const int r = node0 + g;
    int nb = 0, arI = 0;
    float watt = 0.f;
    if (e < KNBR) {
      nb = E_idx[(size_t)r * KNBR + e];
      if (DEC) {
        arI = (nb < np0 + g) ? 1 : 0;
        watt = 1.f;
      } else {
        watt = mask[r] * mask[bb * NN + nb];
      }
    }
    s_nb[t] = nb; s_watt[t] = watt; s_ar[t] = (signed char)arI;
  }
  __syncthreads();

  // per-thread staging geometry (fixed across slabs)
  const int sr = t >> 1, shalf = t & 1;
  const int sg = sr >> 5, se = sr & 31;
  const bool srv = (se < KNBR);
  const int snb = s_nb[sr];
  const bool sar = (bool)s_ar[sr];

  auto src_of = [&](int s) -> const ushort_t* {
    if (!srv) return nullptr;
    const int fc0 = s * 64 + shalf * 32;
    const int seg = fc0 >> 7, off = fc0 & 127;
    if (seg == 0) return hV_in + (size_t)(node0 + sg) * HH + off;
    if (seg == 1) return hE + ((size_t)(node0 + sg) * KNBR + se) * HH + off;
    if (seg == 2) {
      if (DEC) return sar ? (hS + (size_t)(bb * NN + snb) * HH + off) : nullptr;
      return hV_in + (size_t)(bb * NN + snb) * HH + off;
    }
    return (sar ? hV_in : hV_enc) + (size_t)(bb * NN + snb) * HH + off;
  };

  f32x4 acc[4][4];
#pragma unroll
  for (int ni = 0; ni < 4; ++ni) {
    const float bv = b1[wn * 64 + ni * 16 + (lane & 15)];
#pragma unroll
    for (int mi = 0; mi < 4; ++mi) acc[mi][ni] = {bv, bv, bv, bv};
  }

  // ---- GEMM1: double-buffered slabs, 2-deep register prefetch ----
  {
    const short8 z8 = {0, 0, 0, 0, 0, 0, 0, 0};
    short8 a0 = z8, a1 = z8, a2 = z8, a3 = z8;   // holds slab s+1 data in loop
    // prologue: slab 0 -> Xa
    {
      const ushort_t* src = src_of(0);
      if (src) { const short8* p = (const short8*)src; a0 = p[0]; a1 = p[1]; a2 = p[2]; a3 = p[3]; }
      sw_store8(Xa, sr, 128, shalf * 64 + 0, a0);
      sw_store8(Xa, sr, 128, shalf * 64 + 16, a1);
      sw_store8(Xa, sr, 128, shalf * 64 + 32, a2);
      sw_store8(Xa, sr, 128, shalf * 64 + 48, a3);
    }
    // preload slab 1 into regs
    {
      a0 = z8; a1 = z8; a2 = z8; a3 = z8;
      const ushort_t* src = src_of(1);
      if (src) { const short8* p = (const short8*)src; a0 = p[0]; a1 = p[1]; a2 = p[2]; a3 = p[3]; }
    }
    __syncthreads();

    for (int s = 0; s < SLABS; ++s) {
      ushort_t* cur = (s & 1) ? Xb : Xa;
      ushort_t* nxt = (s & 1) ? Xa : Xb;
      // issue slab s+2 loads FIRST (consumed at end of iter s+1)
      short8 b0 = {0, 0, 0, 0, 0, 0, 0, 0}, b1r = b0, b2r = b0, b3r = b0;
      if (s + 2 < SLABS) {
        const ushort_t* src = src_of(s + 2);
        if (src) { const short8* p = (const short8*)src; b0 = p[0]; b1r = p[1]; b2r = p[2]; b3r = p[3]; }
      }
      // MFMA over current slab
#pragma unroll
      for (int kb = 0; kb < 2; ++kb) {
        const int kbg = s * 2 + kb;
        short8 A[4], Bf[4];
#pragma unroll
        for (int mi = 0; mi < 4; ++mi)
          A[mi] = sw_load8(cur, wm * 64 + mi * 16 + (lane & 15), 128, kb * 64 + (lane >> 4) * 16);
#pragma unroll
        for (int ni = 0; ni < 4; ++ni)
          Bf[ni] = *(const short8*)&W1f[(((size_t)kbg * 8 + wn * 4 + ni) * 64 + lane) * 8];
#pragma unroll
        for (int mi = 0; mi < 4; ++mi)
#pragma unroll
          for (int ni = 0; ni < 4; ++ni)
            acc[mi][ni] = __builtin_amdgcn_mfma_f32_16x16x32_bf16(A[mi], Bf[ni], acc[mi][ni], 0, 0, 0);
      }
      // write slab s+1 (in regs a*) into idle buffer, then single barrier
      if (s + 1 < SLABS) {
        sw_store8(nxt, sr, 128, shalf * 64 + 0, a0);
        sw_store8(nxt, sr, 128, shalf * 64 + 16, a1);
        sw_store8(nxt, sr, 128, shalf * 64 + 32, a2);
        sw_store8(nxt, sr, 128, shalf * 64 + 48, a3);
      }
      __syncthreads();
      a0 = b0; a1 = b1r; a2 = b2r; a3 = b3r;
    }
  }

  // write Y1 = relu(.) into union (X buffers dead after final barrier)
#pragma unroll
  for (int mi = 0; mi < 4; ++mi)
#pragma unroll
    for (int ni = 0; ni < 4; ++ni)
#pragma unroll
      for (int q = 0; q < 4; ++q) {
        const int row = wm * 64 + mi * 16 + (lane >> 4) * 4 + q;
        const int col = wn * 64 + ni * 16 + (lane & 15);
        sw_store1(Ys, row, 256, col, f2us(fmaxf(acc[mi][ni][q], 0.f)));
      }
  __syncthreads();

  // ---- GEMM2 ----
#pragma unroll
  for (int ni = 0; ni < 4; ++ni) {
    const float bv = b2[wn * 64 + ni * 16 + (lane & 15)];
#pragma unroll
    for (int mi = 0; mi < 4; ++mi) acc[mi][ni] = {bv, bv, bv, bv};
  }
#pragma unroll
  for (int kb = 0; kb < 4; ++kb) {
    short8 A[4], Bf[4];
#pragma unroll
    for (int mi = 0; mi < 4; ++mi)
      A[mi] = sw_load8(Ys, wm * 64 + mi * 16 + (lane & 15), 256, kb * 64 + (lane >> 4) * 16);
#pragma unroll
    for (int ni = 0; ni < 4; ++ni)
      Bf[ni] = *(const short8*)&W2f[(((size_t)kb * 8 + wn * 4 + ni) * 64 + lane) * 8];
#pragma unroll
    for (int mi = 0; mi < 4; ++mi)
#pragma unroll
      for (int ni = 0; ni < 4; ++ni)
        acc[mi][ni] = __builtin_amdgcn_mfma_f32_16x16x32_bf16(A[mi], Bf[ni], acc[mi][ni], 0, 0, 0);
  }
  __syncthreads();
#pragma unroll
  for (int mi = 0; mi < 4; ++mi)
#pragma unroll
    for (int ni = 0; ni < 4; ++ni)
#pragma unroll
      for (int q = 0; q < 4; ++q) {
        const int row = wm * 64 + mi * 16 + (lane >> 4) * 4 + q;
        const int col = wn * 64 + ni * 16 + (lane & 15);
        sw_store1(Ys, row, 256, col, f2us(fmaxf(acc[mi][ni][q], 0.f)));
      }
  __syncthreads();

  // ---- GEMM3 ----
#pragma unroll
  for (int ni = 0; ni < 4; ++ni) {
    const float bv = b3[wn * 64 + ni * 16 + (lane & 15)];
#pragma unroll
    for (int mi = 0; mi < 4; ++mi) acc[mi][ni] = {bv, bv, bv, bv};
  }
#pragma unroll
  for (int kb = 0; kb < 4; ++kb) {
    short8 A[4], Bf[4];
#pragma unroll
    for (int mi = 0; mi < 4; ++mi)
      A[mi] = sw_load8(Ys, wm * 64 + mi * 16 + (lane & 15), 256, kb * 64 + (lane >> 4) * 16);
#pragma unroll
    for (int ni = 0; ni < 4; ++ni)
      Bf[ni] = *(const short8*)&W3f[(((size_t)kb * 8 + wn * 4 + ni) * 64 + lane) * 8];
#pragma unroll
    for (int mi = 0; mi < 4; ++mi)
#pragma unroll
      for (int ni = 0; ni < 4; ++ni)
        acc[mi][ni] = __builtin_amdgcn_mfma_f32_16x16x32_bf16(A[mi], Bf[ni], acc[mi][ni], 0, 0, 0);
  }
  __syncthreads();  // Ys dead; dhs overlay becomes safe

  // ---- masked sum over edge rows -> dh ----
  float wrow[4][4];
#pragma unroll
  for (int mi = 0; mi < 4; ++mi)
#pragma unroll
    for (int q = 0; q < 4; ++q)
      wrow[mi][q] = s_watt[wm * 64 + mi * 16 + (lane >> 4) * 4 + q];
#pragma unroll
  for (int ni = 0; ni < 4; ++ni) {
    float p0 = 0.f, p1 = 0.f;
#pragma unroll
    for (int q = 0; q < 4; ++q) {
      p0 += wrow[0][q] * acc[0][ni][q] + wrow[1][q] * acc[1][ni][q];
      p1 += wrow[2][q] * acc[2][ni][q] + wrow[3][q] * acc[3][ni][q];
    }
    p0 += __shfl_xor(p0, 16, 64); p0 += __shfl_xor(p0, 32, 64);
    p1 += __shfl_xor(p1, 16, 64); p1 += __shfl_xor(p1, 32, 64);
    if (lane < 16) {
      dhs[(wm * 2 + 0) * HH + wn * 64 + ni * 16 + lane] = p0;
      dhs[(wm * 2 + 1) * HH + wn * 64 + ni * 16 + lane] = p1;
    }
  }
  __syncthreads();

  // ---- LN1: wave wid handles node wid ----
  {
    const int r = node0 + wid;
    const float x0 = us2f(hV_in[(size_t)r * HH + lane]) + dhs[wid * HH + lane] * (1.f / 30.f);
    const float x1 = us2f(hV_in[(size_t)r * HH + lane + 64]) + dhs[wid * HH + lane + 64] * (1.f / 30.f);
    float sm2 = x0 + x1;
#pragma unroll
    for (int m = 32; m >= 1; m >>= 1) sm2 += __shfl_xor(sm2, m, 64);
    const float mu = sm2 * (1.f / HH);
    const float d0 = x0 - mu, d1 = x1 - mu;
    float vv = d0 * d0 + d1 * d1;
#pragma unroll
    for (int m = 32; m >= 1; m >>= 1) vv += __shfl_xor(vv, m, 64);
    const float rs = rsqrtf(vv * (1.f / HH) + LEPS);
    h1out[(size_t)r * HH + lane] = f2us(g1[lane] * d0 * rs + bt1[lane]);
    h1out[(size_t)r * HH + lane + 64] = f2us(g1[lane + 64] * d1 * rs + bt1[lane + 64]);
  }
}

// ---------------- FF kernel: 32 rows/block; bf16 hV out ----------------
__global__ __launch_bounds__(256) void k_ff(
    const ushort_t* __restrict__ h1, const ushort_t* __restrict__ Winf,
    const ushort_t* __restrict__ Wfff,
    const float* __restrict__ bin, const float* __restrict__ bff,
    const float* __restrict__ g2, const float* __restrict__ bt2,
    const float* __restrict__ mask, ushort_t* __restrict__ hV_out)
{
  const int t = threadIdx.x, wid = t >> 6, lane = t & 63;
  const int row0 = blockIdx.x * 32;
  __shared__ alignas(16) ushort_t As[32 * 128];   // 8KB rowB=256
  __shared__ alignas(16) ushort_t Us[32 * 512];   // 32KB rowB=1024; reused as f32 h2

  {
    const int row = t >> 3, oct = t & 7;
    const short8* p = (const short8*)(h1 + (size_t)(row0 + row) * HH + oct * 16);
    sw_store8(As, row, 256, oct * 32, p[0]);
    sw_store8(As, row, 256, oct * 32 + 16, p[1]);
  }
  __syncthreads();

  // GEMM A: wave covers cols wid*128..+127 of N=512
  f32x4 ua[2][8];
#pragma unroll
  for (int ni = 0; ni < 8; ++ni) {
    const float bv = bin[wid * 128 + ni * 16 + (lane & 15)];
#pragma unroll
    for (int mi = 0; mi < 2; ++mi) ua[mi][ni] = {bv, bv, bv, bv};
  }
#pragma unroll
  for (int kb = 0; kb < 4; ++kb) {
    short8 A[2], Bf[8];
#pragma unroll
    for (int mi = 0; mi < 2; ++mi)
      A[mi] = sw_load8(As, mi * 16 + (lane & 15), 256, kb * 64 + (lane >> 4) * 16);
#pragma unroll
    for (int ni = 0; ni < 8; ++ni)
      Bf[ni] = *(const short8*)&Winf[(((size_t)kb * 32 + wid * 8 + ni) * 64 + lane) * 8];
#pragma unroll
    for (int mi = 0; mi < 2; ++mi)
#pragma unroll
      for (int ni = 0; ni < 8; ++ni)
        ua[mi][ni] = __builtin_amdgcn_mfma_f32_16x16x32_bf16(A[mi], Bf[ni], ua[mi][ni], 0, 0, 0);
  }
#pragma unroll
  for (int mi = 0; mi < 2; ++mi)
#pragma unroll
    for (int ni = 0; ni < 8; ++ni)
#pragma unroll
      for (int q = 0; q < 4; ++q) {
        const int row = mi * 16 + (lane >> 4) * 4 + q;
        const int col = wid * 128 + ni * 16 + (lane & 15);
        sw_store1(Us, row, 1024, col, f2us(fmaxf(ua[mi][ni][q], 0.f)));
      }
  __syncthreads();

  // GEMM B: wave covers cols wid*32..+31 of N=128; K=512
  f32x4 fa[2][2];
#pragma unroll
  for (int ni = 0; ni < 2; ++ni) {
    const float bv = bff[wid * 32 + ni * 16 + (lane & 15)];
#pragma unroll
    for (int mi = 0; mi < 2; ++mi) fa[mi][ni] = {bv, bv, bv, bv};
  }
#pragma unroll
  for (int kb = 0; kb < 16; ++kb) {
    short8 A[2], Bf[2];
#pragma unroll
    for (int mi = 0; mi < 2; ++mi)
      A[mi] = sw_load8(Us, mi * 16 + (lane & 15), 1024, kb * 64 + (lane >> 4) * 16);
#pragma unroll
    for (int ni = 0; ni < 2; ++ni)
      Bf[ni] = *(const short8*)&Wfff[(((size_t)kb * 8 + wid * 2 + ni) * 64 + lane) * 8];
#pragma unroll
    for (int mi = 0; mi < 2; ++mi)
#pragma unroll
      for (int ni = 0; ni < 2; ++ni)
        fa[mi][ni] = __builtin_amdgcn_mfma_f32_16x16x32_bf16(A[mi], Bf[ni], fa[mi][ni], 0, 0, 0);
  }
  __syncthreads();  // all reads of Us done

  float* h2 = (float*)Us;
#pragma unroll
  for (int mi = 0; mi < 2; ++mi)
#pragma unroll
    for (int ni = 0; ni < 2; ++ni)
#pragma unroll
      for (int q = 0; q < 4; ++q) {
        const int row = mi * 16 + (lane >> 4) * 4 + q;
        const int col = wid * 32 + ni * 16 + (lane & 15);
        h2[row * HH + col] = us2f(h1[(size_t)(row0 + row) * HH + col]) + fa[mi][ni][q];
      }
  __syncthreads();

  // LN2 + mask: 8 threads per row
  {
    const int row = t >> 3, oct = t & 7;
    float x[16], sm = 0.f;
#pragma unroll
    for (int i = 0; i < 16; ++i) { x[i] = h2[row * HH + oct * 16 + i]; sm += x[i]; }
    sm += __shfl_xor(sm, 1, 64); sm += __shfl_xor(sm, 2, 64); sm += __shfl_xor(sm, 4, 64);
    const float mu = sm * (1.f / HH);
    float vv = 0.f;
#pragma unroll
    for (int i = 0; i < 16; ++i) { const float d = x[i] - mu; vv += d * d; }
    vv += __shfl_xor(vv, 1, 64); vv += __shfl_xor(vv, 2, 64); vv += __shfl_xor(vv, 4, 64);
    const float rs = rsqrtf(vv * (1.f / HH) + LEPS);
    const float m1v = mask[row0 + row];
#pragma unroll
    for (int i = 0; i < 16; ++i) {
      const int col = oct * 16 + i;
      hV_out[(size_t)(row0 + row) * HH + col] =
          f2us((g2[col] * (x[i] - mu) * rs + bt2[col]) * m1v);
    }
  }
}

// ---------------- logits + log_softmax ----------------
__global__ __launch_bounds__(64) void k_out(
    const ushort_t* __restrict__ hV, const float* __restrict__ Wout,
    const float* __restrict__ bout, float* __restrict__ out)
{
  const int r = blockIdx.x;
  const int lane = threadIdx.x;
  __shared__ alignas(16) float sx[HH];
  sx[lane] = us2f(hV[(size_t)r * HH + lane]);
  sx[lane + 64] = us2f(hV[(size_t)r * HH + lane + 64]);
  __syncthreads();
  float logit = -1e30f;
  if (lane < NV) {
    float acc = bout[lane];
    for (int i = 0; i < HH; ++i) acc += sx[i] * Wout[i * NV + lane];
    logit = acc;
  }
  float mx = logit;
#pragma unroll
  for (int m = 32; m >= 1; m >>= 1) mx = fmaxf(mx, __shfl_xor(mx, m, 64));
  float e = (lane < NV) ? expf(logit - mx) : 0.f;
  float s = e;
#pragma unroll
  for (int m = 32; m >= 1; m >>= 1) s += __shfl_xor(s, m, 64);
  if (lane < NV) out[(size_t)r * NV + lane] = logit - mx - logf(s);
}

// ---------------- launcher ----------------
extern "C" void kernel_launch(void* const* d_in, const int* in_sizes, int n_in,
                              void* d_out, int out_size, void* d_ws, size_t ws_size,
                              hipStream_t stream)
{
  const int* S = (const int*)d_in[0];
  const float* V = (const float*)d_in[1];
  const float* E = (const float*)d_in[2];
  const int* E_idx = (const int*)d_in[3];
  const float* mask = (const float*)d_in[4];
  const float* Wv = (const float*)d_in[5];
  const float* bv = (const float*)d_in[6];
  const float* We = (const float*)d_in[7];
  const float* be = (const float*)d_in[8];
  const float* Wse = (const float*)d_in[9];
  const float* Wout = (const float*)d_in[10];
  const float* bout = (const float*)d_in[11];
  const float* eW[14];
  const float* dW[14];
  for (int i = 0; i < 14; ++i) eW[i] = (const float*)d_in[12 + i];
  for (int i = 0; i < 14; ++i) dW[i] = (const float*)d_in[26 + i];

  // ws layout (bytes):
  //   hE    bf16 : 62,914,560 @ 0
  //   hVa16 bf16 :  2,097,152 @ 62,914,560
  //   hVb16 bf16 :  2,097,152 @ 65,011,712
  //   h1    bf16 :  2,097,152 @ 67,108,864
  //   hS    bf16 :  2,097,152 @ 69,206,016
  //   WP    bf16 :  2,719,744 @ 71,303,168   (end 74,022,912)
  char* w = (char*)d_ws;
  ushort_t* hE = (ushort_t*)w;
  ushort_t* hVa = (ushort_t*)(w + 62914560u);
  ushort_t* hVb = (ushort_t*)(w + 65011712u);
  ushort_t* h1 = (ushort_t*)(w + 67108864u);
  ushort_t* hS = (ushort_t*)(w + 69206016u);
  ushort_t* WP = (ushort_t*)(w + 71303168u);

  const int R = 8 * NN;  // 8192

  // ---- build merged prep table (32 tensors) ----
  PrepTab tab;
  int ti = 0, blk = 0;
  auto addT = [&](const float* src, unsigned dstOff, int K, int nshift) {
    tab.src[ti] = src; tab.dstOff[ti] = dstOff;
    tab.blk0[ti] = blk; tab.nshift[ti] = nshift;
    blk += (K << nshift) >> 8;
    ++ti;
  };
  for (int l = 0; l < 3; ++l) {
    const unsigned base = l * 212992u;
    addT(eW[0] + l * 384 * 128, base + 0,      384, 7);
    addT(eW[2] + l * 128 * 128, base + 49152,  128, 7);
    addT(eW[4] + l * 128 * 128, base + 65536,  128, 7);
    addT(eW[6] + l * 128 * 512, base + 81920,  128, 9);
    addT(eW[8] + l * 512 * 128, base + 147456, 512, 7);
  }
  for (int l = 0; l < 3; ++l) {
    const unsigned base = 638976u + l * 229376u;
    addT(dW[0] + l * 512 * 128, base + 0,      512, 7);
    addT(dW[2] + l * 128 * 128, base + 65536,  128, 7);
    addT(dW[4] + l * 128 * 128, base + 81920,  128, 7);
    addT(dW[6] + l * 128 * 512, base + 98304,  128, 9);
    addT(dW[8] + l * 512 * 128, base + 163840, 512, 7);
  }
  addT(We, 1327104u, 128, 7);
  addT(Wv, 1343488u, 128, 7);
  k_prep_all<<<blk, 256, 0, stream>>>(tab, WP);  // blk == 5312

  // ---- embeddings ----
  k_gemm64<<<R / 64, 256, 0, stream>>>(V, WP + 1343488, bv, hVa);        // h_V (bf16)
  k_hs<<<R * 32 / 256, 256, 0, stream>>>(S, Wse, hS);                     // h_S
  k_gemm64<<<R * KNBR / 64, 256, 0, stream>>>(E, WP + 1327104, be, hE);  // h_E

  // encoder (in-place on hVa)
  for (int l = 0; l < 3; ++l) {
    const ushort_t* base = WP + l * 212992;
    k_msg<0><<<2048, 256, 0, stream>>>(hVa, hVa, hS, hE,
        base, base + 49152, base + 65536,
        eW[1] + l * 128, eW[3] + l * 128, eW[5] + l * 128,
        eW[10] + l * 128, eW[11] + l * 128, E_idx, mask, h1);
    k_ff<<<256, 256, 0, stream>>>(h1, base + 81920, base + 147456,
        eW[7] + l * 512, eW[9] + l * 128, eW[12] + l * 128, eW[13] + l * 128,
        mask, hVa);
  }
  // decoder: hV_enc = hVa (preserved); state rotates into hVb
  for (int l = 0; l < 3; ++l) {
    const ushort_t* base = WP + 638976 + l * 229376;
    const ushort_t* hin = (l == 0) ? hVa : hVb;
    k_msg<1><<<2048, 256, 0, stream>>>(hin, hVa, hS, hE,
        base, base + 65536, base + 81920,
        dW[1] + l * 128, dW[3] + l * 128, dW[5] + l * 128,
        dW[10] + l * 128, dW[11] + l * 128, E_idx, mask, h1);
    k_ff<<<256, 256, 0, stream>>>(h1, base + 98304, base + 163840,
        dW[7] + l * 512, dW[9] + l * 128, dW[12] + l * 128, dW[13] + l * 128,
        mask, hVb);
  }

  k_out<<<R, 64, 0, stream>>>(hVb, Wout, bout, (float*)d_out);

  (void)in_sizes; (void)n_in; (void)out_size; (void)ws_size;
}